// Round 2
// 359.677 us; speedup vs baseline: 1.0730x; 1.0730x over previous
//
#include <hip/hip_runtime.h>
#include <math.h>

#define IN_F  8192
#define OUT_F 8192
#define NEG_BIG (-9e15f)

// ws layout (in floats):
//   [0      .. 32767]  h' = h @ W            (4 x 8192)
//   [32768  .. 32773]  pair sums s01,s02,s03,s12,s13,s23 (squared distances)
//   [32784  .. ]       split-K partials: KC x 4 x 8192
#define HP_OFF   0
#define PAIR_OFF 32768
#define PART_OFF 32784   // byte offset 131136, 16B-aligned

// Native clang vector type: __builtin_nontemporal_load requires a pointer to
// scalar/vector-of-scalar, not HIP_vector_type (a struct). W is pure
// streaming (zero reuse); the nt hint keeps the 256 MB W stream from
// evicting the 16 MB split-K partials out of L3, so reduce_pairs reads them
// at cache BW instead of re-fetching from HBM.
typedef float floatx4 __attribute__((ext_vector_type(4)));

__device__ __forceinline__ floatx4 ntload4(const float* p) {
  return __builtin_nontemporal_load(reinterpret_cast<const floatx4*>(p));
}

// ---------------------------------------------------------------------------
// Kernel 1: split-K GEMM  h'[i][j] = sum_k h[i][k] * W[k][j]
// grid = (8 column-tiles, KC k-chunks), block = 256 threads, 4 cols/thread.
// h chunk staged to LDS once per block (broadcast ds_read_b128 thereafter);
// W loads are non-temporal float4 (16B/lane coalesced, no cache pollution).
// KC=128 -> 1024 blocks -> 4 waves/SIMD for latency hiding; partial
// round-trip (16MB) stays in L3.
// ---------------------------------------------------------------------------
template <int KC>
__global__ __launch_bounds__(256) void gemm_partial_kernel(
    const float* __restrict__ h, const float* __restrict__ W,
    float* __restrict__ ws) {
  constexpr int KLEN = IN_F / KC;
  const int jt = blockIdx.x;                       // 0..7
  const int kc = blockIdx.y;                       // 0..KC-1
  const int j  = jt * 1024 + threadIdx.x * 4;      // column group of 4
  const int k0 = kc * KLEN;

  if (jt == 0 && kc == 0 && threadIdx.x < 6)
    ws[PAIR_OFF + threadIdx.x] = 0.0f;

  // Stage h[0..3][k0 .. k0+KLEN) into LDS (uniform across lanes afterwards).
  __shared__ float hs[4][KLEN];
#pragma unroll
  for (int t = threadIdx.x; t < 4 * KLEN; t += 256) {
    const int r = t / KLEN;
    const int c = t % KLEN;
    hs[r][c] = h[r * IN_F + k0 + c];
  }
  __syncthreads();

  float4 a0 = make_float4(0.f, 0.f, 0.f, 0.f);
  float4 a1 = a0, a2 = a0, a3 = a0;

  const float* wp = W + (size_t)k0 * OUT_F + j;

#pragma unroll 2
  for (int kk = 0; kk < KLEN; kk += 4) {
    float hr0[4], hr1[4], hr2[4], hr3[4];
    *(float4*)hr0 = *(const float4*)&hs[0][kk];   // broadcast, conflict-free
    *(float4*)hr1 = *(const float4*)&hs[1][kk];
    *(float4*)hr2 = *(const float4*)&hs[2][kk];
    *(float4*)hr3 = *(const float4*)&hs[3][kk];
#pragma unroll
    for (int u = 0; u < 4; ++u) {
      const floatx4 w = ntload4(wp + (size_t)u * OUT_F);
      a0.x += hr0[u] * w.x; a0.y += hr0[u] * w.y; a0.z += hr0[u] * w.z; a0.w += hr0[u] * w.w;
      a1.x += hr1[u] * w.x; a1.y += hr1[u] * w.y; a1.z += hr1[u] * w.z; a1.w += hr1[u] * w.w;
      a2.x += hr2[u] * w.x; a2.y += hr2[u] * w.y; a2.z += hr2[u] * w.z; a2.w += hr2[u] * w.w;
      a3.x += hr3[u] * w.x; a3.y += hr3[u] * w.y; a3.z += hr3[u] * w.z; a3.w += hr3[u] * w.w;
    }
    wp += 4 * OUT_F;
  }

  // Partials are consumed by the very next kernel: plain (cached) stores.
  float* p = ws + PART_OFF + (size_t)(kc * 4) * OUT_F + j;
  *(float4*)(p + 0 * OUT_F) = a0;
  *(float4*)(p + 1 * OUT_F) = a1;
  *(float4*)(p + 2 * OUT_F) = a2;
  *(float4*)(p + 3 * OUT_F) = a3;
}

// ---------------------------------------------------------------------------
// Kernel 2: reduce split-K partials -> h', and fuse the 6 pairwise
// squared-distance reductions. grid = 32 blocks x 256 threads; wave i
// (of 4) handles row i, each lane owns 4 consecutive columns (float4
// loads -- Guideline 13). Partials are L3-resident (16 MB, kept warm by
// the nt W loads), so this is a couple of microseconds.
// ---------------------------------------------------------------------------
__global__ __launch_bounds__(256) void reduce_pairs_kernel(
    float* __restrict__ ws, int KC) {
  const int i  = threadIdx.x >> 6;                 // 0..3 (one wave per row)
  const int jl = threadIdx.x & 63;
  const int j  = (blockIdx.x * 64 + jl) * 4;       // 4-col group

  float4 s = make_float4(0.f, 0.f, 0.f, 0.f);
  const float* p = ws + PART_OFF + (size_t)i * OUT_F + j;
#pragma unroll 8
  for (int kc = 0; kc < KC; ++kc) {
    const float4 v = *(const float4*)(p + (size_t)kc * 4 * OUT_F);
    s.x += v.x; s.y += v.y; s.z += v.z; s.w += v.w;
  }

  *(float4*)(ws + HP_OFF + i * OUT_F + j) = s;

  __shared__ float4 sh[4][64];
  sh[i][jl] = s;
  __syncthreads();

  if (i == 0) {
    const float4 h0 = sh[0][jl], h1 = sh[1][jl], h2 = sh[2][jl], h3 = sh[3][jl];
#define DSUM(A, B) \
    (((A).x-(B).x)*((A).x-(B).x) + ((A).y-(B).y)*((A).y-(B).y) + \
     ((A).z-(B).z)*((A).z-(B).z) + ((A).w-(B).w)*((A).w-(B).w))
    float d01 = DSUM(h0, h1);
    float d02 = DSUM(h0, h2);
    float d03 = DSUM(h0, h3);
    float d12 = DSUM(h1, h2);
    float d13 = DSUM(h1, h3);
    float d23 = DSUM(h2, h3);
#undef DSUM
#pragma unroll
    for (int off = 32; off > 0; off >>= 1) {
      d01 += __shfl_down(d01, off);
      d02 += __shfl_down(d02, off);
      d03 += __shfl_down(d03, off);
      d12 += __shfl_down(d12, off);
      d13 += __shfl_down(d13, off);
      d23 += __shfl_down(d23, off);
    }
    if (jl == 0) {
      atomicAdd(&ws[PAIR_OFF + 0], d01);
      atomicAdd(&ws[PAIR_OFF + 1], d02);
      atomicAdd(&ws[PAIR_OFF + 2], d03);
      atomicAdd(&ws[PAIR_OFF + 3], d12);
      atomicAdd(&ws[PAIR_OFF + 4], d13);
      atomicAdd(&ws[PAIR_OFF + 5], d23);
    }
  }
}

// ---------------------------------------------------------------------------
// Kernel 3: per-column combine. Every thread recomputes the tiny 3x3
// column-softmax in registers, mixes rows 1..3, copies row 0, and thread 0
// writes the three scalar outputs.
// ---------------------------------------------------------------------------
__global__ __launch_bounds__(256) void combine_kernel(
    const float* __restrict__ ws, const int* __restrict__ adj,
    float* __restrict__ out) {
  const int j = blockIdx.x * blockDim.x + threadIdx.x;   // 0..8191

  const float d01 = sqrtf(ws[PAIR_OFF + 0]);
  const float d02 = sqrtf(ws[PAIR_OFF + 1]);
  const float d03 = sqrtf(ws[PAIR_OFF + 2]);
  const float d12 = sqrtf(ws[PAIR_OFF + 3]);
  const float d13 = sqrtf(ws[PAIR_OFF + 4]);
  const float d23 = sqrtf(ws[PAIR_OFF + 5]);

  const float v01 = d12 + 0.5f * (d01 + d02);
  const float v02 = d13 + 0.5f * (d01 + d03);
  const float v12 = d23 + 0.5f * (d02 + d03);

  float e[3][3] = {{0.f, v01, v02}, {v01, 0.f, v12}, {v02, v12, 0.f}};
  float a[3][3];
#pragma unroll
  for (int r = 0; r < 3; ++r)
#pragma unroll
    for (int c = 0; c < 3; ++c)
      a[r][c] = (adj[r * 3 + c] > 0) ? e[r][c] : NEG_BIG;

  float att[3][3];
#pragma unroll
  for (int c = 0; c < 3; ++c) {
    const float m  = fmaxf(a[0][c], fmaxf(a[1][c], a[2][c]));
    const float e0 = expf(a[0][c] - m);
    const float e1 = expf(a[1][c] - m);
    const float e2 = expf(a[2][c] - m);
    const float z  = e0 + e1 + e2;
    att[0][c] = e0 / z; att[1][c] = e1 / z; att[2][c] = e2 / z;
  }

  const float h0 = ws[HP_OFF + j];
  const float h1 = ws[HP_OFF + OUT_F + j];
  const float h2 = ws[HP_OFF + 2 * OUT_F + j];
  const float h3 = ws[HP_OFF + 3 * OUT_F + j];

  out[j] = h0;
  out[OUT_F + j]     = att[0][0] * h1 + att[0][1] * h2 + att[0][2] * h3;
  out[2 * OUT_F + j] = att[1][0] * h1 + att[1][1] * h2 + att[1][2] * h3;
  out[3 * OUT_F + j] = att[2][0] * h1 + att[2][1] * h2 + att[2][2] * h3;

  if (j == 0) {
    out[4 * OUT_F + 0] = v01;   // face_Rhand
    out[4 * OUT_F + 1] = v02;   // face_Lhand
    out[4 * OUT_F + 2] = v12;   // Rhand_Lhand
  }
}

extern "C" void kernel_launch(void* const* d_in, const int* in_sizes, int n_in,
                              void* d_out, int out_size, void* d_ws, size_t ws_size,
                              hipStream_t stream) {
  const float* h   = (const float*)d_in[0];   // [4, 8192] fp32
  const int*   adj = (const int*)d_in[1];     // [3, 3] int32
  const float* W   = (const float*)d_in[2];   // [8192, 8192] fp32
  float* out = (float*)d_out;
  float* ws  = (float*)d_ws;

  // Pick split-K factor based on available workspace (deterministic per run).
  const size_t need128 = (size_t)(PART_OFF + 128 * 4 * OUT_F) * sizeof(float);
  const size_t need64  = (size_t)(PART_OFF + 64 * 4 * OUT_F) * sizeof(float);

  if (ws_size >= need128) {
    gemm_partial_kernel<128><<<dim3(8, 128), 256, 0, stream>>>(h, W, ws);
    reduce_pairs_kernel<<<32, 256, 0, stream>>>(ws, 128);
  } else if (ws_size >= need64) {
    gemm_partial_kernel<64><<<dim3(8, 64), 256, 0, stream>>>(h, W, ws);
    reduce_pairs_kernel<<<32, 256, 0, stream>>>(ws, 64);
  } else {
    gemm_partial_kernel<16><<<dim3(8, 16), 256, 0, stream>>>(h, W, ws);
    reduce_pairs_kernel<<<32, 256, 0, stream>>>(ws, 16);
  }
  combine_kernel<<<32, 256, 0, stream>>>(ws, adj, out);
}